// Round 7
// baseline (145.078 us; speedup 1.0000x reference)
//
#include <hip/hip_runtime.h>

// B=8, H=W=128, Cin=128, Cout=256, 3x3 stride2 pad1 -> OH=OW=64.
// Implicit GEMM: M=32768, N=256, K=1152 (9 taps x 128).
// d_out (f32): out_feats[32768*256] | out_coords[32768*3] | alpha[1]
// R14: 2 BLOCKS PER CU. m-tile 64 x n-tile 128, 8 waves (512thr), band = 3 rows
//      x 128 x 128B = 48KB (nx=-1 pad handled by register predicate, not LDS),
//      B dbuf 2x16KB -> LDS exactly 80KB -> 2 resident blocks/CU. 1024 blocks
//      (4/CU): band-load (HBM) of one block overlaps tap-loop (LDS) / epilogue
//      (HBM-W) of the other. R13 showed intra-block TLP is not the binder;
//      cross-block phase overlap is the remaining serialization.

#define OUT_FEATS_ELEMS (32768 * 256)
#define OUT_COORDS_OFF  OUT_FEATS_ELEMS
#define ALPHA_OFF       (OUT_FEATS_ELEMS + 32768 * 3)

#define BW_BYTES   (18 * 16384)

typedef float v16f __attribute__((ext_vector_type(16)));

__device__ __forceinline__ unsigned pk4fp8(float a, float b, float c, float d) {
    unsigned u = 0;
    u = __builtin_amdgcn_cvt_pk_fp8_f32(a, b, u, false);  // bytes 0,1
    u = __builtin_amdgcn_cvt_pk_fp8_f32(c, d, u, true);   // bytes 2,3
    return u;
}

#define GLOAD_LDS16(SRC, DST)                                                  \
    __builtin_amdgcn_global_load_lds(                                          \
        (const __attribute__((address_space(1))) void*)(SRC),                  \
        (__attribute__((address_space(3))) void*)(DST), 16, 0, 0)

// ---- weight prep: pre-swizzled fp8 B images + coords + alpha ----
// Image[t=nb*9+tap][row 0..127][ch 0..7] (16B chunks):
//   fp8 of w[k = tap*128 + (ch^(row&7))*16 + j][n = nb*128 + row], j=0..15
__global__ void wprep_kernel(const float* __restrict__ w,
                             const float* __restrict__ alpha,
                             unsigned char* __restrict__ Bw,
                             float* __restrict__ out) {
    int cid = blockIdx.x * 256 + threadIdx.x;     // 0..36863
    if (cid < 32768) {                            // coords
        int b = cid >> 12, iy = (cid >> 6) & 63, ix = cid & 63;
        float* c = out + OUT_COORDS_OFF + (size_t)cid * 3;
        c[0] = (float)b; c[1] = (float)iy; c[2] = (float)ix;
        if (cid == 0) out[ALPHA_OFF] = alpha[0];
    }
    if (cid < 18432) {                            // 18 images x 128 rows x 8 chunks
        int ch  = cid & 7;
        int row = (cid >> 3) & 127;
        int t   = cid >> 10;                      // 0..17 = nb*9 + tap
        int nb  = (t >= 9) ? 1 : 0;
        int tap = t - 9 * nb;
        int chp = ch ^ (row & 7);
        int n   = (nb << 7) + row;
        int kb  = (tap << 7) + (chp << 4);
        unsigned u[4];
#pragma unroll
        for (int q = 0; q < 4; ++q) {
            float f0 = w[(size_t)(kb + 4 * q + 0) * 256 + n];
            float f1 = w[(size_t)(kb + 4 * q + 1) * 256 + n];
            float f2 = w[(size_t)(kb + 4 * q + 2) * 256 + n];
            float f3 = w[(size_t)(kb + 4 * q + 3) * 256 + n];
            u[q] = pk4fp8(f0, f1, f2, f3);
        }
        uint4 r; r.x = u[0]; r.y = u[1]; r.z = u[2]; r.w = u[3];
        *(uint4*)(Bw + (size_t)cid * 16) = r;
    }
}

// ---- coords for fallback path ----
__global__ void coords_alpha_kernel(float* __restrict__ out, const float* __restrict__ alpha) {
    int i = blockIdx.x * 256 + threadIdx.x;
    int b = i >> 12, iy = (i >> 6) & 63, ix = i & 63;
    float* c = out + OUT_COORDS_OFF + (size_t)i * 3;
    c[0] = (float)b; c[1] = (float)iy; c[2] = (float)ix;
    if (i == 0) out[ALPHA_OFF] = alpha[0];
}

// ---- fused conv GEMM, 2 blocks/CU ----
// Aband layout: [r 0..2][nxq 0..127][128B of k-chans], chunk c stored at
//   c ^ (((nxq+1)>>1)&7). nxq = input_nx (no pad column; nx=-1 handled in regs).
// r = ny - (2*iy - 1). Row r=0 zeroed when iy==0 (ny=-1).
__global__ __launch_bounds__(512, 4) void gemm_conv_kernel(
    const float* __restrict__ feats,         // fp32 [B*128*128][128]
    const unsigned char* __restrict__ Bw,    // pre-swizzled fp8 B images (18 x 16KB)
    float* __restrict__ out)                 // [32768][256]
{
    __shared__ unsigned char Aband[3 * 128 * 128];   // 49,152 B
    __shared__ unsigned char Bs[2][128 * 128];       // 2 x 16,384 B  (total 80KB)

    const int tid  = threadIdx.x;
    const int bid  = blockIdx.x;             // 0..1023
    // XCD-aware: XCD (bid&7) owns batch bb=(bid&7). nb-pairs (bid, bid+512) same XCD.
    const int my   = ((bid & 7) << 6) + ((bid >> 3) & 63);   // 0..511 m-tile
    const int nb   = bid >> 9;                               // 0..1
    const int m0   = my << 6;
    const int n0   = nb << 7;
    const int bb   = my >> 6;                // == bid & 7
    const int iy   = my & 63;                // output row of this tile

    const int lane = tid & 63, wave = tid >> 6;  // wave 0..7
    const int wm   = (wave >> 2) << 5;       // 0 / 32
    const int wn   = (wave & 3) << 5;        // 0 / 32 / 64 / 96
    const int l31  = lane & 31;
    const int hh   = lane >> 5;              // k-half select
    const int xorl = l31 & 7;

    // ---- B staging machinery (2 x global_load_lds per wave per tap) ----
    // wave w stages Bs rows [w*16, w*16+16) of image nb*9+tap.
    const unsigned char* bsrc0 = Bw + ((size_t)(nb * 9) << 14)
                                    + ((size_t)wave << 11) + ((size_t)lane << 4);
    auto stageB = [&](int tap, int buf) {
        const unsigned char* bs = bsrc0 + ((size_t)tap << 14);
        unsigned char* bdst = Bs[buf] + (wave << 11);
#pragma unroll
        for (int q = 0; q < 2; ++q)
            GLOAD_LDS16(bs + (q << 10), bdst + (q << 10));
    };

    stageB(0, 0);                             // overlap tap-0 B DMA with band phase

    // ---- phase 0: zero ny=-1 row (iy==0 blocks only) ----
    if (iy == 0) {
        for (int z = tid; z < 1024; z += 512) {
            const int nx = z >> 3, c = z & 7;
            uint4 zz; zz.x = 0u; zz.y = 0u; zz.z = 0u; zz.w = 0u;
            *(uint4*)(Aband + (nx << 7) + ((c ^ (((nx + 1) >> 1) & 7)) << 4)) = zz;
        }
    }

    // ---- phase 1: load + convert the 3-row fp32 band into LDS ----
    {
        const int ny0 = (iy << 1) - 1;            // input row of band r=0
        auto loadBand = [&](int vstart, int iters) {
#pragma unroll 4
            for (int it = 0; it < iters; ++it) {
                const int o   = (tid + (it << 9)) << 4;  // byte offset in valid region
                const int r   = vstart + (o >> 16);      // band row (64KB per row)
                const int br  = o & 65535;
                const int nx  = br >> 9;
                const int ch0 = (br & 511) >> 2;         // float idx 0..124 step 4
                const float4 f = *(const float4*)(feats +
                    ((((size_t)(bb << 14) + (ny0 + r) * 128 + nx)) << 7) + ch0);
                const unsigned u = pk4fp8(f.x, f.y, f.z, f.w);
                const int c = ch0 >> 4;
                *(unsigned*)(Aband + ((r * 128 + nx) << 7)
                             + ((c ^ (((nx + 1) >> 1) & 7)) << 4) + (ch0 & 15)) = u;
            }
        };
        if (iy == 0) loadBand(1, 16); else loadBand(0, 24);
    }
    __syncthreads();                          // band + tap0 B visible to all waves

    v16f acc = (v16f)(0.0f);

    auto computeTap = [&](int buf, int dy, int dx) {
        const int r   = dy + 1;                          // band row, wave-uniform
        const int ixv = wm + l31;                        // 0..63 output x
        const int nxq = (ixv << 1) + dx;                 // -1..127 input x
        const bool pad = (nxq < 0);
        const int nxs = pad ? 0 : nxq;
        const int abase = ((r << 7) + nxs) << 7;
        const int akey  = ((nxq + 1) >> 1) & 7;          // == (nxp>>1)&7
#pragma unroll
        for (int seg = 0; seg < 8; ++seg) {   // K=128 -> 8 x (32x32x16)
            long long a0 = *(const long long*)(Aband + abase + ((seg ^ akey) << 4) + (hh << 3));
            if (pad) a0 = 0LL;
            long long b0 = *(const long long*)(Bs[buf] + ((wn + l31) << 7)
                                               + ((seg ^ xorl) << 4) + (hh << 3));
            __builtin_amdgcn_s_setprio(1);
            acc = __builtin_amdgcn_mfma_f32_32x32x16_fp8_fp8(a0, b0, acc, 0, 0, 0);
            __builtin_amdgcn_s_setprio(0);
        }
    };

#pragma unroll
    for (int tap = 0; tap < 9; ++tap) {
        if (tap < 8) {
            stageB(tap + 1, (tap + 1) & 1);
            // own 2 oldest (tap's B) drained; next tap's 2 stay in flight.
            asm volatile("s_waitcnt vmcnt(2)\ns_barrier" ::: "memory");
        } else {
            asm volatile("s_waitcnt vmcnt(0)\ns_barrier" ::: "memory");
        }
        computeTap(tap & 1, tap / 3 - 1, tap % 3 - 1);
        if (tap < 8)                          // protect buf reuse by next stage
            asm volatile("s_barrier" ::: "memory");
    }

    // epilogue: 32x32 D layout col=lane&31, row=(reg&3)+8*(reg>>2)+4*(lane>>5)  [m74/m101]
    // nt stores: output stream does not allocate/thrash L2.
    {
        const int gcol = n0 + wn + l31;
#pragma unroll
        for (int r = 0; r < 16; ++r) {
            const int grow = m0 + wm + (r & 3) + ((r >> 2) << 3) + (hh << 2);
            __builtin_nontemporal_store(acc[r], &out[(size_t)grow * 256 + gcol]);
        }
    }
}

// ---- fallback: direct fp32 conv ----
__global__ void naive_conv_kernel(const float* __restrict__ feats,
                                  const float* __restrict__ w,
                                  float* __restrict__ out) {
    int m = blockIdx.x;
    int n = threadIdx.x;
    int bb = m >> 12, iy = (m >> 6) & 63, ix = m & 63;
    float acc = 0.f;
    for (int tap = 0; tap < 9; ++tap) {
        int ny = 2 * iy + tap / 3 - 1;
        int nx = 2 * ix + tap % 3 - 1;
        if ((unsigned)ny < 128u && (unsigned)nx < 128u) {
            const float* fr = feats + ((size_t)((bb << 14) + (ny << 7) + nx) << 7);
            const float* wr = w + tap * 32768 + n;
            for (int c = 0; c < 128; ++c) acc += fr[c] * wr[c * 256];
        }
    }
    out[(size_t)m * 256 + n] = acc;
}

extern "C" void kernel_launch(void* const* d_in, const int* in_sizes, int n_in,
                              void* d_out, int out_size, void* d_ws, size_t ws_size,
                              hipStream_t stream) {
    const float* feats  = (const float*)d_in[0];
    const float* weight = (const float*)d_in[1];
    const float* alpha  = (const float*)d_in[2];
    float* out = (float*)d_out;

    const size_t NEED = (size_t)BW_BYTES;
    if (ws_size >= NEED) {
        unsigned char* Bw = (unsigned char*)d_ws;
        wprep_kernel<<<144, 256, 0, stream>>>(weight, alpha, Bw, out);
        gemm_conv_kernel<<<1024, 512, 0, stream>>>(feats, Bw, out);
    } else {
        coords_alpha_kernel<<<128, 256, 0, stream>>>(out, alpha);
        naive_conv_kernel<<<32768, 256, 0, stream>>>(feats, weight, out);
    }
}

// Round 8
// 128.115 us; speedup vs baseline: 1.1324x; 1.1324x over previous
//
#include <hip/hip_runtime.h>

// B=8, H=W=128, Cin=128, Cout=256, 3x3 stride2 pad1 -> OH=OW=64.
// Implicit GEMM: M=32768, N=256, K=1152 (9 taps x 128).
// d_out (f32): out_feats[32768*256] | out_coords[32768*3] | alpha[1]
// R15: revert to R12 base (best). Two fixes:
//  (1) 4-bit LDS swizzle (16B-chunk XOR + 8B-half XOR) on A band and B images
//      -> LDS reads go 4-way -> 2-way(free) bank aliasing (R12 had 2.36M conflicts).
//  (2) band pipelining (T14): rows r0,r2 loaded up front (taps 0-2 need only
//      those); r1,r3 issued at tap0 / written after compute(2); r4 issued at
//      tap3 / written after compute(5). Counted vmcnt ladder keeps B prefetch.

#define OUT_FEATS_ELEMS (32768 * 256)
#define OUT_COORDS_OFF  OUT_FEATS_ELEMS
#define ALPHA_OFF       (OUT_FEATS_ELEMS + 32768 * 3)

#define BW_BYTES   (18 * 16384)

typedef float v16f __attribute__((ext_vector_type(16)));

__device__ __forceinline__ unsigned pk4fp8(float a, float b, float c, float d) {
    unsigned u = 0;
    u = __builtin_amdgcn_cvt_pk_fp8_f32(a, b, u, false);  // bytes 0,1
    u = __builtin_amdgcn_cvt_pk_fp8_f32(c, d, u, true);   // bytes 2,3
    return u;
}

#define GLOAD_LDS16(SRC, DST)                                                  \
    __builtin_amdgcn_global_load_lds(                                          \
        (const __attribute__((address_space(1))) void*)(SRC),                  \
        (__attribute__((address_space(3))) void*)(DST), 16, 0, 0)

#define WAITBAR_(N) asm volatile("s_waitcnt vmcnt(" #N ")\n\ts_barrier" ::: "memory")
#define WAITBAR(N)  WAITBAR_(N)
#define BAR()       asm volatile("s_barrier" ::: "memory")
#define LGKMBAR()   asm volatile("s_waitcnt lgkmcnt(0)\n\ts_barrier" ::: "memory")

// ---- weight prep: pre-swizzled fp8 B images + coords + alpha ----
// Image[t=nb*9+tap][row 0..127][phys chunk 0..7] (16B):
//   logical chunk (ch^(row&7)); within it, 8B halves swapped when ((row>>3)&1).
//   word q holds w[k = tap*128 + (ch^(row&7))*16 + 4*(q^(hb<<1)) + j][n], j=0..3
__global__ void wprep_kernel(const float* __restrict__ w,
                             const float* __restrict__ alpha,
                             unsigned char* __restrict__ Bw,
                             float* __restrict__ out) {
    int cid = blockIdx.x * 256 + threadIdx.x;     // 0..36863
    if (cid < 32768) {                            // coords
        int b = cid >> 12, iy = (cid >> 6) & 63, ix = cid & 63;
        float* c = out + OUT_COORDS_OFF + (size_t)cid * 3;
        c[0] = (float)b; c[1] = (float)iy; c[2] = (float)ix;
        if (cid == 0) out[ALPHA_OFF] = alpha[0];
    }
    if (cid < 18432) {                            // 18 images x 128 rows x 8 chunks
        int ch  = cid & 7;
        int row = (cid >> 3) & 127;
        int t   = cid >> 10;                      // 0..17 = nb*9 + tap
        int nb  = (t >= 9) ? 1 : 0;
        int tap = t - 9 * nb;
        int chp = ch ^ (row & 7);
        int hb  = (row >> 3) & 1;
        int n   = (nb << 7) + row;
        int kb  = (tap << 7) + (chp << 4);
        unsigned u[4];
#pragma unroll
        for (int q = 0; q < 4; ++q) {
            int kq = kb + 4 * (q ^ (hb << 1));    // half-swap when hb=1
            float f0 = w[(size_t)(kq + 0) * 256 + n];
            float f1 = w[(size_t)(kq + 1) * 256 + n];
            float f2 = w[(size_t)(kq + 2) * 256 + n];
            float f3 = w[(size_t)(kq + 3) * 256 + n];
            u[q] = pk4fp8(f0, f1, f2, f3);
        }
        uint4 r; r.x = u[0]; r.y = u[1]; r.z = u[2]; r.w = u[3];
        *(uint4*)(Bw + (size_t)cid * 16) = r;
    }
}

// ---- coords for fallback path ----
__global__ void coords_alpha_kernel(float* __restrict__ out, const float* __restrict__ alpha) {
    int i = blockIdx.x * 256 + threadIdx.x;
    int b = i >> 12, iy = (i >> 6) & 63, ix = i & 63;
    float* c = out + OUT_COORDS_OFF + (size_t)i * 3;
    c[0] = (float)b; c[1] = (float)iy; c[2] = (float)ix;
    if (i == 0) out[ALPHA_OFF] = alpha[0];
}

// ---- fused conv GEMM: persistent LDS A-band (5 rows, fp8, 4-bit swizzle),
//      pipelined band fill, B double-buffered, counted vmcnt ladder ----
// Aband layout: [r 0..4][nxp 0..129][128B]. key4=(nxp>>1)&15.
//   logical chunk c, half h stored at phys chunk c^(key4&7), half h^(key4>>3).
// r = ny - (2*iy0 - 1). nxp = nx+1 (nxp=0 = zero pad col). Row 0 zeroed if iy0==0.
__global__ __launch_bounds__(512, 1) void gemm_conv_kernel(
    const float* __restrict__ feats,         // fp32 [B*128*128][128]
    const unsigned char* __restrict__ Bw,    // pre-swizzled fp8 B images (18 x 16KB)
    float* __restrict__ out)                 // [32768][256]
{
    __shared__ unsigned char Aband[5 * 130 * 128];   // 83,200 B
    __shared__ unsigned char Bs[2][256 * 128];       // 2 x 32,768 B

    const int tid  = threadIdx.x;
    const int bid  = blockIdx.x;             // 0..255
    // XCD-aware: XCD (bid&7) owns batch bb=(bid&7).
    const int my   = ((bid & 7) << 5) + (bid >> 3);
    const int m0   = my << 7;
    const int bb   = my >> 5;                // == bid & 7
    const int iy0  = ((my & 31) << 1);       // 0..62 even

    const int lane = tid & 63, wave = tid >> 6;  // wave 0..7
    const int wm   = (wave >> 2) << 6;       // 0 / 64
    const int wn   = (wave & 3) << 6;        // 0 / 64 / 128 / 192
    const int l31  = lane & 31;
    const int hh   = lane >> 5;              // k-half select
    const int xorl = l31 & 7;
    const int bhalf = (hh ^ ((l31 >> 3) & 1)) << 3;   // B phys 8B-half offset

    // ---- B staging (4 x global_load_lds per wave per tap) ----
    const unsigned char* bsrc0 = Bw + ((size_t)((wave >> 2) * 9) << 14)
                                    + ((size_t)(wave & 3) << 12) + ((size_t)lane << 4);
    auto stageB = [&](int tap, int buf) {
        const unsigned char* bs = bsrc0 + ((size_t)tap << 14);
        unsigned char* bdst = Bs[buf] + (wave << 12);
#pragma unroll
        for (int q = 0; q < 4; ++q)
            GLOAD_LDS16(bs + (q << 10), bdst + (q << 10));
    };

    // ---- band row load/convert helpers (8 float4 per thread per row) ----
    const int ny0 = (iy0 << 1) - 1;
    auto issueRow = [&](int r, float4* f) {
        const int ny = ny0 + r;
#pragma unroll
        for (int it = 0; it < 8; ++it) {
            const int idx = (it << 9) + tid;      // 0..4095
            const int nx  = idx >> 5;
            const int c4  = (idx & 31) << 2;      // float index 0..124 step 4
            f[it] = *(const float4*)(feats +
                ((((size_t)(bb << 14) + ny * 128 + nx)) << 7) + c4);
        }
    };
    auto writeRow = [&](int r, const float4* f) {
#pragma unroll
        for (int it = 0; it < 8; ++it) {
            const int idx = (it << 9) + tid;
            const int nx  = idx >> 5;
            const int c4  = (idx & 31) << 2;
            const unsigned u = pk4fp8(f[it].x, f[it].y, f[it].z, f[it].w);
            const int nxp  = nx + 1;
            const int key4 = (nxp >> 1) & 15;
            const int boff = ((r * 130 + nxp) << 7)
                + (((c4 >> 4) ^ (key4 & 7)) << 4)
                + (((((c4 >> 3) & 1) ^ (key4 >> 3)) & 1) << 3)
                + (c4 & 7);
            *(unsigned*)(Aband + boff) = u;
        }
    };

    // ---- prologue: B(0) DMA, zero pads, rows r0 & r2 (needed by taps 0-2) ----
    stageB(0, 0);
    if (tid < 40) {                          // nxp=0 pad column: 5 rows x 8 chunks
        const int r = tid >> 3, c = tid & 7;
        uint4 z; z.x = 0u; z.y = 0u; z.z = 0u; z.w = 0u;
        *(uint4*)(Aband + ((r * 130) << 7) + (c << 4)) = z;
    }
    if (iy0 == 0) {                          // row r=0 (ny=-1): zero all 16,640 B
        for (int z = tid; z < 1040; z += 512) {
            uint4 zz; zz.x = 0u; zz.y = 0u; zz.z = 0u; zz.w = 0u;
            *(uint4*)(Aband + z * 16) = zz;
        }
    }
    float4 fA[8], fB[8];
    if (iy0 > 0) issueRow(0, fA);
    issueRow(2, fB);
    if (iy0 > 0) writeRow(0, fA);
    writeRow(2, fB);
    __syncthreads();                         // band r0,r2 + B(0) all visible

    v16f acc[2][2];
#pragma unroll
    for (int i = 0; i < 2; i++)
#pragma unroll
        for (int j = 0; j < 2; j++) acc[i][j] = (v16f)(0.0f);

    auto computeTap = [&](int buf, int dy, int dx) {
        const int bandrow = (wm >> 5) + dy + 1;          // wave-uniform
        int abase[2], kc[2];
#pragma unroll
        for (int i = 0; i < 2; ++i) {
            const int ixv  = (i << 5) + l31;
            const int nxp  = (ixv << 1) + dx + 1;        // 0..128
            const int key4 = (nxp >> 1) & 15;
            abase[i] = ((bandrow * 130 + nxp) << 7) + ((hh ^ (key4 >> 3)) << 3);
            kc[i]    = key4 & 7;
        }
#pragma unroll
        for (int seg = 0; seg < 8; ++seg) {   // K=128 -> 8 x (32x32x16)
            long long a[2], b2[2];
#pragma unroll
            for (int i = 0; i < 2; i++)
                a[i] = *(const long long*)(Aband + abase[i] + ((seg ^ kc[i]) << 4));
#pragma unroll
            for (int j = 0; j < 2; j++)
                b2[j] = *(const long long*)(Bs[buf] + ((wn + (j << 5) + l31) << 7)
                                            + ((seg ^ xorl) << 4) + bhalf);
            __builtin_amdgcn_s_setprio(1);
#pragma unroll
            for (int i = 0; i < 2; i++)
#pragma unroll
                for (int j = 0; j < 2; j++)
                    acc[i][j] = __builtin_amdgcn_mfma_f32_32x32x16_fp8_fp8(a[i], b2[j], acc[i][j], 0, 0, 0);
            __builtin_amdgcn_s_setprio(0);
        }
    };

    // ---- 9 taps, hand-scheduled. vmcnt queue notes per phase. ----
    // tap0: queue after issues = B1(4), r1(8), r3(8); B0 already drained.
    stageB(1, 1); issueRow(1, fA); issueRow(3, fB);
    BAR();
    computeTap(0, -1, -1); BAR();
    // tap1: +B2 -> B1,r16,B2; drain B1, keep 20.
    stageB(2, 0); WAITBAR(20);
    computeTap(1, -1, 0); BAR();
    // tap2: +B3 -> r16,B2,B3; drain r16+B2 (writes need r16), keep B3=4.
    stageB(3, 1); WAITBAR(4);
    computeTap(0, -1, 1);
    writeRow(1, fA); writeRow(3, fB);
    LGKMBAR();                               // r1,r3 visible for taps 3-5
    // tap3: +B4,r4 -> B3,B4,r4(8); drain B3, keep 12.
    stageB(4, 0); issueRow(4, fA); WAITBAR(12);
    computeTap(1, 0, -1); BAR();
    // tap4: +B5 -> B4,r4,B5; drain B4, keep 12.
    stageB(5, 1); WAITBAR(12);
    computeTap(0, 0, 0); BAR();
    // tap5: +B6 -> r4,B5,B6; drain r4+B5 (writes need r4), keep B6=4.
    stageB(6, 0); WAITBAR(4);
    computeTap(1, 0, 1);
    writeRow(4, fA);
    LGKMBAR();                               // r4 visible for taps 6-8
    // tap6: +B7 -> B6,B7; drain B6, keep 4.
    stageB(7, 1); WAITBAR(4);
    computeTap(0, 1, -1); BAR();
    // tap7: +B8 -> B7,B8; drain B7, keep 4.
    stageB(8, 0); WAITBAR(4);
    computeTap(1, 1, 0); BAR();
    // tap8: drain B8.
    WAITBAR(0);
    computeTap(0, 1, 1);

    // epilogue: 32x32 D layout col=lane&31, row=(reg&3)+8*(reg>>2)+4*(lane>>5)  [m74/m101]
    // nt stores: output stream does not allocate/thrash L2.
#pragma unroll
    for (int i = 0; i < 2; i++)
#pragma unroll
        for (int j = 0; j < 2; j++) {
            const int gcol = wn + (j << 5) + l31;
#pragma unroll
            for (int r = 0; r < 16; ++r) {
                const int grow = m0 + wm + (i << 5) + (r & 3) + ((r >> 2) << 3) + (hh << 2);
                __builtin_nontemporal_store(acc[i][j][r], &out[(size_t)grow * 256 + gcol]);
            }
        }
}

// ---- fallback: direct fp32 conv ----
__global__ void naive_conv_kernel(const float* __restrict__ feats,
                                  const float* __restrict__ w,
                                  float* __restrict__ out) {
    int m = blockIdx.x;
    int n = threadIdx.x;
    int bb = m >> 12, iy = (m >> 6) & 63, ix = m & 63;
    float acc = 0.f;
    for (int tap = 0; tap < 9; ++tap) {
        int ny = 2 * iy + tap / 3 - 1;
        int nx = 2 * ix + tap % 3 - 1;
        if ((unsigned)ny < 128u && (unsigned)nx < 128u) {
            const float* fr = feats + ((size_t)((bb << 14) + (ny << 7) + nx) << 7);
            const float* wr = w + tap * 32768 + n;
            for (int c = 0; c < 128; ++c) acc += fr[c] * wr[c * 256];
        }
    }
    out[(size_t)m * 256 + n] = acc;
}

extern "C" void kernel_launch(void* const* d_in, const int* in_sizes, int n_in,
                              void* d_out, int out_size, void* d_ws, size_t ws_size,
                              hipStream_t stream) {
    const float* feats  = (const float*)d_in[0];
    const float* weight = (const float*)d_in[1];
    const float* alpha  = (const float*)d_in[2];
    float* out = (float*)d_out;

    const size_t NEED = (size_t)BW_BYTES;
    if (ws_size >= NEED) {
        unsigned char* Bw = (unsigned char*)d_ws;
        wprep_kernel<<<144, 256, 0, stream>>>(weight, alpha, Bw, out);
        gemm_conv_kernel<<<256, 512, 0, stream>>>(feats, Bw, out);
    } else {
        coords_alpha_kernel<<<128, 256, 0, stream>>>(out, alpha);
        naive_conv_kernel<<<32768, 256, 0, stream>>>(feats, weight, out);
    }
}